// Round 7
// baseline (3611.204 us; speedup 1.0000x reference)
//
#include <hip/hip_runtime.h>
#include <hip/hip_bf16.h>

// ---------------------------------------------------------------------------
// PoseFeatureNet R7:
//  - k_lstm_f6: 4-way column-split recurrence. 32 WGs = 8 groups x 4 quarters
//    (g = blk%8, q = blk>>3 so a group's 4 WGs share blk%8 -> same XCD).
//    WG owns 64 j x 4 gates, FULL K=256; its Whh slice (128 KB bf16) lives in
//    LDS (128 B/cyc) -- no per-step L2 Whh stream, no K-split partials.
//    Gate transpose via ds_bpermute (no LDS bounce). h exchange 4KB/12KB per
//    step via global + wave-granular release/acquire flags (R6 protocol),
//    intra-XCD. 2 barriers/step.
//  - k_wfrag / k_gemm_mfma epilogue repacked for this layout.
//  - k_gcnfused / k_lstm_b / k_head unchanged.
// ---------------------------------------------------------------------------

#define TT 256
#define BB 128
#define NNODE 17
#define DD 2176    // 17*128
#define LHID 256
#define G4 1024    // 4*LHID
#define NCLS 625

typedef unsigned short u16t;

__device__ __constant__ int ESRC[19] = {15,13,16,14,11,5,6,5,5,6,7,8,1,0,0,1,2,3,4};
__device__ __constant__ int EDST[19] = {13,11,14,12,12,11,12,6,7,8,9,10,2,1,2,3,4,5,6};
__device__ __constant__ float DEGF[17] = {1,2,3,2,2,2,3,2,2,2,2,3,4,2,2,1,1};

__device__ inline float lo2f(unsigned u){ union{unsigned x; float f;} c; c.x = u << 16; return c.f; }
__device__ inline float hi2f(unsigned u){ union{unsigned x; float f;} c; c.x = u & 0xffff0000u; return c.f; }
__device__ inline u16t f2b(float f){
    __hip_bfloat16 h = __float2bfloat16(f);
    u16t s; __builtin_memcpy(&s, &h, 2); return s;
}
__device__ inline float b2f(u16t s){ union{unsigned x; float f;} c; c.x = ((unsigned)s) << 16; return c.f; }
__device__ inline unsigned pack2(float a, float b){
    return (unsigned)f2b(a) | ((unsigned)f2b(b) << 16);
}
__device__ inline float fsig(float x){ return __fdividef(1.f, 1.f + __expf(-x)); }
__device__ inline float ftanh(float x){ float e = __expf(2.f*x); return 1.f - __fdividef(2.f, e + 1.f); }
__device__ inline float sigm(float x){ return 1.f / (1.f + expf(-x)); }

typedef __attribute__((ext_vector_type(8))) short bf16x8;
typedef __attribute__((ext_vector_type(4))) float f32x4;

__device__ inline void gload16(const void* g, void* l){
    __builtin_amdgcn_global_load_lds(
        (const __attribute__((address_space(1))) void*)g,
        (__attribute__((address_space(3))) void*)l, 16, 0, 0);
}

// ----------------------------------------------------------- zero sync flags
__global__ void k_zeroflags(int* __restrict__ flags){
    flags[threadIdx.x] = 0;   // 512 ints
}

// --------------------------------------------- W2 -> bf16 transposed [n][k]
__global__ void k_w2t(const float* __restrict__ W2, __hip_bfloat16* __restrict__ W2Tb){
    int g = blockIdx.x * 256 + threadIdx.x;   // 16384
    int k = g >> 7, n = g & 127;
    W2Tb[n * 128 + k] = __float2bfloat16(W2[g]);
}

// ------------------- Whh -> bf16 fragments, R7 packing
// slot = (((q*8 + w)*2 + nt)*8 + kc)*64 + lane   (32768 slots x 16B)
// lane: gate = (lane&15)>>2, jj = lane&3
//   col = gate*256 + q*64 + w*8 + nt*4 + jj
//   k   = kc*32 + (lane>>4)*8 + i   (i = 0..7)
__global__ void k_wfrag(const float* __restrict__ Whh, u16t* __restrict__ WTfrag){
    int slot = blockIdx.x * 256 + threadIdx.x;   // 32768
    int lane = slot & 63;
    int kc   = (slot >> 6) & 7;
    int nt   = (slot >> 9) & 1;
    int w    = (slot >> 10) & 7;
    int q    = slot >> 13;
    int gate = (lane & 15) >> 2, jj = lane & 3;
    int col  = gate*256 + q*64 + w*8 + nt*4 + jj;
    int k0   = kc*32 + (lane >> 4)*8;
    const float* src = Whh + (size_t)col * 256 + k0;
    float4 f0 = *(const float4*)src;
    float4 f1 = *(const float4*)(src + 4);
    uint4 o;
    o.x = pack2(f0.x, f0.y); o.y = pack2(f0.z, f0.w);
    o.z = pack2(f1.x, f1.y); o.w = pack2(f1.z, f1.w);
    *(uint4*)(WTfrag + (size_t)slot * 8) = o;
}

// ------------------------------------------------------------ fused GCN block
__global__ __launch_bounds__(512) void k_gcnfused(
    const float* __restrict__ pose1, const float* __restrict__ pose2,
    const float* __restrict__ W1, const float* __restrict__ b1,
    const float* __restrict__ b2, const __hip_bfloat16* __restrict__ W2Tb,
    __hip_bfloat16* __restrict__ feats)
{
    __shared__ u16t  Abuf[272][136];
    __shared__ u16t  BsmT[128][136];
    __shared__ float ps4[2][16][17][4];
    __shared__ float araw[17*128];
    __shared__ float araw2[17*128];
    __shared__ float As[289];

    const int tid = threadIdx.x;
    const int blk = blockIdx.x;
    const int t   = blk >> 3;
    const int bc  = blk & 7;

    for (int idx = tid; idx < 1632; idx += 512){
        int p_ = idx >= 816 ? 1 : 0;
        int r  = idx - p_ * 816;
        int bl = r / 51, i = r - bl * 51;
        int n = i / 3, c = i - n * 3;
        const float* src = p_ ? pose2 : pose1;
        ps4[p_][bl][n][c] = src[(size_t)((bc*16 + bl) * TT + t) * 51 + i];
    }
    {
        const uint4* src = (const uint4*)W2Tb;
        for (int r = 0; r < 2; ++r){
            int f0 = (tid + r * 512) * 16;
            int n = f0 >> 7, k0 = f0 & 127;
            uint4 v0 = src[(tid + r*512)*2 + 0];
            uint4 v1 = src[(tid + r*512)*2 + 1];
            *(uint4*)&BsmT[n][k0]     = v0;
            *(uint4*)&BsmT[n][k0 + 8] = v1;
        }
    }
    if (bc == 0 && tid < 289){
        int i = tid / 17, j = tid - (tid/17)*17;
        float a = (i == j) ? 1.0f / DEGF[i] : 0.0f;
        for (int e = 0; e < 19; ++e)
            if (EDST[e] == i && ESRC[e] == j)
                a += 1.0f / sqrtf(DEGF[i] * DEGF[j]);
        As[tid] = a;
    }

    const int h = tid & 127;
    const int q = tid >> 7;
    const float w10 = W1[h], w11 = W1[128 + h], w12 = W1[256 + h];
    const float b1h = b1[h];
    __syncthreads();

    float a2st[5];
    int nl[5], nv = 0;
    for (int s = 0; s < 5; ++s){ int n = q + 4*s; if (n < NNODE) nl[nv++] = n; }
    for (int s = 0; s < nv; ++s){
        int n = nl[s];
        for (int bl = 0; bl < 16; ++bl){
            float4 p1 = *(const float4*)&ps4[0][bl][n][0];
            float4 p2 = *(const float4*)&ps4[1][bl][n][0];
            float a1 = p1.x*w10 + p1.y*w11 + p1.z*w12;
            float a2 = p2.x*w10 + p2.y*w11 + p2.z*w12;
            if (bc == 0 && bl == 0){
                araw[n*128 + h] = a1;
                a2st[s] = a2;
            } else {
                float r1 = fmaxf(a1 + b1h, 0.f);
                float r2 = fmaxf(a2 + b1h, 0.f);
                Abuf[n*16 + bl][h] = f2b(0.5f*(r1 + r2));
            }
        }
    }
    __syncthreads();
    if (bc == 0){
        for (int s = 0; s < nv; ++s){
            int n = nl[s]; float a = 0.f;
            #pragma unroll
            for (int j = 0; j < NNODE; ++j) a += As[n*17 + j] * araw[j*128 + h];
            araw2[n*128 + h] = fmaxf(a + b1h, 0.f);
        }
    }
    __syncthreads();
    if (bc == 0){
        for (int s = 0; s < nv; ++s){
            int n = nl[s]; float a = 0.f;
            #pragma unroll
            for (int j = 0; j < NNODE; ++j) a += As[n*17 + j] * araw2[j*128 + h];
            float r2 = fmaxf(a2st[s] + b1h, 0.f);
            Abuf[n*16 + 0][h] = f2b(0.5f*(a + r2));
        }
    }
    __syncthreads();

    const int w = tid >> 6, l = tid & 63;
    const int l15 = l & 15, q8 = (l >> 4) * 8, q4 = (l >> 4) * 4;
    float bias[8];
    #pragma unroll
    for (int nt = 0; nt < 8; ++nt) bias[nt] = b2[nt*16 + l15];

    bf16x8 Bf[4][8];
    #pragma unroll
    for (int kc = 0; kc < 4; ++kc)
        #pragma unroll
        for (int nt = 0; nt < 8; ++nt)
            Bf[kc][nt] = *(const bf16x8*)&BsmT[nt*16 + l15][kc*32 + q8];

    u16t* Cb = (u16t*)feats;
    for (int mt = w; mt < NNODE; mt += 8){
        f32x4 acc[8];
        #pragma unroll
        for (int nt = 0; nt < 8; ++nt) acc[nt] = (f32x4){0.f,0.f,0.f,0.f};
        #pragma unroll
        for (int kc = 0; kc < 4; ++kc){
            bf16x8 a = *(const bf16x8*)&Abuf[mt*16 + l15][kc*32 + q8];
            #pragma unroll
            for (int nt = 0; nt < 8; ++nt)
                acc[nt] = __builtin_amdgcn_mfma_f32_16x16x32_bf16(a, Bf[kc][nt], acc[nt], 0,0,0);
        }
        #pragma unroll
        for (int nt = 0; nt < 8; ++nt)
            #pragma unroll
            for (int r = 0; r < 4; ++r){
                size_t row = (size_t)(blk*16 + q4 + r) * NNODE + mt;
                Cb[row*128 + nt*16 + l15] = f2b(acc[nt][r] + bias[nt]);
            }
    }
}

// ------------------------------------------------- pre_f GEMM: bf16 MFMA
// R7 epilogue: col = gate*256 + jg; q = jg>>6, jl = jg&63; b: g = b>>4, s = b&15
// off = t*131072 + g*16384 + q*4096 + jl*64 + s*4 + gate
__global__ __launch_bounds__(256) void k_gemm_mfma(
    const __hip_bfloat16* __restrict__ A, const float* __restrict__ Bw,
    const float* __restrict__ bi1, const float* __restrict__ bi2,
    u16t* __restrict__ pre2)
{
    __shared__ u16t Asm[128][32];
    __shared__ u16t Bsm[128][32];
    const int tid = threadIdx.x;
    const int w = tid >> 6;
    const int l = tid & 63;
    const size_t m0 = (size_t)blockIdx.x * 128;
    const int n0 = blockIdx.y * 128;
    const int mw = (w >> 1) * 64;
    const int nw = (w & 1) * 64;

    f32x4 acc[4][4];
    #pragma unroll
    for (int s = 0; s < 4; ++s)
        #pragma unroll
        for (int t_ = 0; t_ < 4; ++t_)
            acc[s][t_] = (f32x4){0.f, 0.f, 0.f, 0.f};

    const u16t* Ab = (const u16t*)A;
    const int arow = w*32 + (l>>2);
    const int akoff = (l&3)*8;
    const int brow = w*32 + (l>>1);
    const int bko  = (l&1)*16;
    const int fr = l & 15, fq = (l >> 4) * 8;

    for (int kt = 0; kt < DD; kt += 32){
        gload16(Ab + (m0 + arow)*DD + kt + akoff,      &Asm[arow][akoff]);
        gload16(Ab + (m0 + arow + 16)*DD + kt + akoff, &Asm[arow+16][akoff]);
        const float* bp = Bw + (size_t)(n0 + brow)*DD + kt + bko;
        float4 f0 = *(const float4*)bp;
        float4 f1 = *(const float4*)(bp+4);
        float4 f2 = *(const float4*)(bp+8);
        float4 f3 = *(const float4*)(bp+12);
        uint4 o0, o1;
        o0.x = pack2(f0.x,f0.y); o0.y = pack2(f0.z,f0.w);
        o0.z = pack2(f1.x,f1.y); o0.w = pack2(f1.z,f1.w);
        o1.x = pack2(f2.x,f2.y); o1.y = pack2(f2.z,f2.w);
        o1.z = pack2(f3.x,f3.y); o1.w = pack2(f3.z,f3.w);
        *(uint4*)&Bsm[brow][bko]   = o0;
        *(uint4*)&Bsm[brow][bko+8] = o1;
        __syncthreads();

        bf16x8 af[4], bf[4];
        #pragma unroll
        for (int s = 0; s < 4; ++s) af[s] = *(const bf16x8*)&Asm[mw + s*16 + fr][fq];
        #pragma unroll
        for (int t_ = 0; t_ < 4; ++t_) bf[t_] = *(const bf16x8*)&Bsm[nw + t_*16 + fr][fq];
        #pragma unroll
        for (int s = 0; s < 4; ++s)
            #pragma unroll
            for (int t_ = 0; t_ < 4; ++t_)
                acc[s][t_] = __builtin_amdgcn_mfma_f32_16x16x32_bf16(af[s], bf[t_], acc[s][t_], 0, 0, 0);
        __syncthreads();
    }

    const int cr = (l >> 4) * 4;
    const int cc = l & 15;
    const int tIdx = blockIdx.x;
    #pragma unroll
    for (int t_ = 0; t_ < 4; ++t_){
        int col = n0 + nw + t_*16 + cc;
        float bias = bi1[col] + bi2[col];
        int gate = col >> 8;
        int jg   = col & 255;
        size_t cbase = (size_t)tIdx*131072 + (size_t)(jg >> 6)*4096
                     + (size_t)(jg & 63)*64 + gate;
        #pragma unroll
        for (int s = 0; s < 4; ++s)
            #pragma unroll
            for (int r = 0; r < 4; ++r){
                int b = mw + s*16 + cr + r;
                pre2[cbase + (size_t)(b>>4)*16384 + (size_t)(b&15)*4]
                    = f2b(acc[s][t_][r] + bias);
            }
    }
}

// --------------------- backward LSTM: one step from zero state (unchanged)
__global__ __launch_bounds__(256) void k_lstm_b(
    const __hip_bfloat16* __restrict__ feats255,
    const float* __restrict__ Wih_b,
    const float* __restrict__ bih_b, const float* __restrict__ bhh_b,
    float* __restrict__ h_b)
{
    __shared__ float fs[DD];
    const int tid = threadIdx.x;
    const int b = blockIdx.x;
    const unsigned* fbu = (const unsigned*)(feats255 + (size_t)b * DD);
    for (int i = tid; i < DD/2; i += 256){
        unsigned u = fbu[i];
        fs[2*i] = lo2f(u); fs[2*i+1] = hi2f(u);
    }
    __syncthreads();

    const int w = tid >> 6, lane = tid & 63;
    const int j = blockIdx.y * 4 + w;
    const float* Wi = Wih_b + (size_t)j * DD;
    const float* Wg = Wih_b + (size_t)(512 + j) * DD;
    const float* Wo = Wih_b + (size_t)(768 + j) * DD;
    float si = 0.f, sg = 0.f, so = 0.f;
    #pragma unroll 2
    for (int i = 0; i < 34; ++i){
        int k = lane + i*64;
        float f = fs[k];
        si += f * Wi[k]; sg += f * Wg[k]; so += f * Wo[k];
    }
    #pragma unroll
    for (int off = 32; off > 0; off >>= 1){
        si += __shfl_down(si, off);
        sg += __shfl_down(sg, off);
        so += __shfl_down(so, off);
    }
    if (lane == 0){
        float zi = si + bih_b[j]       + bhh_b[j];
        float zg = sg + bih_b[512 + j] + bhh_b[512 + j];
        float zo = so + bih_b[768 + j] + bhh_b[768 + j];
        float c = sigm(zi) * tanhf(zg);
        h_b[(size_t)b*LHID + j] = sigm(zo) * tanhf(c);
    }
}

// ------------------- forward LSTM R7: LDS-resident Whh, 4-way col split
// grid 32: g = blk&7 (sample group, 16 samples), q = blk>>3 (col quarter).
// 512 threads (8 waves). Wave w owns 8 j's (jl = w*8..w*8+8) x 4 gates =
// 2 n-tiles; full K=256 (h hi+lo -> 32 MFMA/wave/step).
__global__ __launch_bounds__(512, 2) void k_lstm_f6(
    const u16t* __restrict__ pre2,
    const u16t* __restrict__ WTfrag,
    unsigned* __restrict__ hx,     // [wg 32][slot 2][1024] u32 (hi|lo<<16)
    int* __restrict__ flags,       // [wg 32] * 16-int stride
    float* __restrict__ hout)      // (128,256)
{
    __shared__ u16t Bs[65536];       // 128 KB: Whh quarter, frag-packed
    __shared__ u16t hAhi[16][272];   // [sample][k], pad 272 (16B-aligned rows)
    __shared__ u16t hAlo[16][272];

    const int tid = threadIdx.x;
    const int wgid = blockIdx.x;
    const int g = wgid & 7, q = wgid >> 3;
    const int w = tid >> 6, l = tid & 63;
    const int q16 = l >> 4, l15 = l & 15;
    const int jj = l & 3, sL = l >> 2;       // post-transpose identity

    // stage Whh quarter into LDS (one-time, 128 KB)
    {
        const uint4* src = (const uint4*)WTfrag + (size_t)q * 8192;
        uint4* dst = (uint4*)Bs;
        for (int i = tid; i < 8192; i += 512) dst[i] = src[i];
    }
    for (int i = tid; i < 16*272; i += 512){
        ((u16t*)hAhi)[i] = 0; ((u16t*)hAlo)[i] = 0;
    }

    float cst[2] = {0.f, 0.f};
    unsigned* hx_my = hx + (size_t)wgid * 2048;
    int* flag_my = flags + wgid * 16;
    const int qp0 = (q + 1) & 3, qp1 = (q + 2) & 3, qp2 = (q + 3) & 3;
    const unsigned* hx_p0 = hx + (size_t)(qp0*8 + g) * 2048;
    const unsigned* hx_p1 = hx + (size_t)(qp1*8 + g) * 2048;
    const unsigned* hx_p2 = hx + (size_t)(qp2*8 + g) * 2048;
    int* flag_p0 = flags + (qp0*8 + g) * 16;
    int* flag_p1 = flags + (qp1*8 + g) * 16;
    int* flag_p2 = flags + (qp2*8 + g) * 16;
    // pre2 per-lane base: lane (nt): jl = w*8 + nt*4 + jj, sample sL
    const size_t pbase = (size_t)g*16384 + (size_t)q*4096
                       + (size_t)(w*8 + jj)*64 + (size_t)sL*4;
    __syncthreads();

    #pragma unroll 1
    for (int t = 0; t < TT; ++t){
        // prefetch pre (4 gates packed as uint2 per (j,s))
        union { uint2 v; u16t s4[4]; } pr[2];
        {
            const u16t* pp = pre2 + (size_t)t*131072 + pbase;
            pr[0].v = *(const uint2*)pp;          // nt=0: jl = w*8+jj
            pr[1].v = *(const uint2*)(pp + 256);  // nt=1: jl = w*8+4+jj
        }

        // z = [h_hi; h_lo] @ Whh_slice  (full K, 2 n-tiles)
        f32x4 acc[2];
        acc[0] = (f32x4){0.f,0.f,0.f,0.f};
        acc[1] = (f32x4){0.f,0.f,0.f,0.f};
        #pragma unroll
        for (int kc = 0; kc < 8; ++kc){
            bf16x8 ah = *(const bf16x8*)&hAhi[l15][kc*32 + q16*8];
            bf16x8 al = *(const bf16x8*)&hAlo[l15][kc*32 + q16*8];
            bf16x8 b0 = *(const bf16x8*)&Bs[(((w*2+0)*8 + kc)*64 + l)*8];
            bf16x8 b1 = *(const bf16x8*)&Bs[(((w*2+1)*8 + kc)*64 + l)*8];
            acc[0] = __builtin_amdgcn_mfma_f32_16x16x32_bf16(ah, b0, acc[0], 0,0,0);
            acc[1] = __builtin_amdgcn_mfma_f32_16x16x32_bf16(ah, b1, acc[1], 0,0,0);
            acc[0] = __builtin_amdgcn_mfma_f32_16x16x32_bf16(al, b0, acc[0], 0,0,0);
            acc[1] = __builtin_amdgcn_mfma_f32_16x16x32_bf16(al, b1, acc[1], 0,0,0);
        }

        // in-register transpose: lane (jj,sL) gathers its 4 gates per tile
        float z[2][4];
        #pragma unroll
        for (int nt = 0; nt < 2; ++nt)
            #pragma unroll
            for (int gt = 0; gt < 4; ++gt){
                const int srcl = gt*4 + jj + ((sL >> 2) << 4);
                #pragma unroll
                for (int r = 0; r < 4; ++r){
                    int v = __builtin_amdgcn_ds_bpermute(srcl*4, __float_as_int(acc[nt][r]));
                    if ((sL & 3) == r) z[nt][gt] = __int_as_float(v);
                }
            }

        // gates (c, h in registers)
        float hhv[2]; u16t hb[2], lb[2];
        #pragma unroll
        for (int nt = 0; nt < 2; ++nt){
            float zi = z[nt][0] + b2f(pr[nt].s4[0]);
            float zf = z[nt][1] + b2f(pr[nt].s4[1]);
            float zg = z[nt][2] + b2f(pr[nt].s4[2]);
            float zo = z[nt][3] + b2f(pr[nt].s4[3]);
            float cn = fsig(zf)*cst[nt] + fsig(zi)*ftanh(zg);
            cst[nt] = cn;
            hhv[nt] = fsig(zo)*ftanh(cn);
            hb[nt] = f2b(hhv[nt]);
            lb[nt] = f2b(hhv[nt] - b2f(hb[nt]));
        }

        __syncthreads();   // B1: all MFMA reads of hA(t) complete

        const int slot = (t + 1) & 1;
        if (t < TT - 1){
            // own h -> LDS + publish to partners
            unsigned* hw = hx_my + slot*1024;
            #pragma unroll
            for (int nt = 0; nt < 2; ++nt){
                const int jl = w*8 + nt*4 + jj;
                const int jgl = q*64 + jl;
                hAhi[sL][jgl] = hb[nt];
                hAlo[sL][jgl] = lb[nt];
                hw[jl*16 + sL] = (unsigned)hb[nt] | ((unsigned)lb[nt] << 16);
            }
            if (l == 0)
                __hip_atomic_fetch_add(flag_my, 1, __ATOMIC_RELEASE, __HIP_MEMORY_SCOPE_AGENT);

            // import partners' h (12 KB total; 6 u32 per thread)
            const int thr = 8*(t + 1);
            while (__hip_atomic_load(flag_p0, __ATOMIC_ACQUIRE, __HIP_MEMORY_SCOPE_AGENT) < thr ||
                   __hip_atomic_load(flag_p1, __ATOMIC_ACQUIRE, __HIP_MEMORY_SCOPE_AGENT) < thr ||
                   __hip_atomic_load(flag_p2, __ATOMIC_ACQUIRE, __HIP_MEMORY_SCOPE_AGENT) < thr)
                __builtin_amdgcn_s_sleep(2);
            {
                const unsigned* srcs[3] = { hx_p0 + slot*1024, hx_p1 + slot*1024, hx_p2 + slot*1024 };
                const int qps[3] = { qp0, qp1, qp2 };
                #pragma unroll
                for (int p = 0; p < 3; ++p){
                    uint2 v = *(const uint2*)(srcs[p] + tid*2);
                    const int i0 = tid*2;
                    const int jl0 = i0 >> 4, s0 = i0 & 15;
                    const int jg0 = qps[p]*64 + jl0;
                    hAhi[s0][jg0]     = (u16t)(v.x & 0xffff);
                    hAlo[s0][jg0]     = (u16t)(v.x >> 16);
                    hAhi[s0+1][jg0]   = (u16t)(v.y & 0xffff);   // i0+1: same jl, s+1
                    hAlo[s0+1][jg0]   = (u16t)(v.y >> 16);
                }
            }
        } else {
            #pragma unroll
            for (int nt = 0; nt < 2; ++nt){
                const int jgl = q*64 + w*8 + nt*4 + jj;
                hout[((size_t)(g*16 + sL))*LHID + jgl] = hhv[nt];
            }
        }
        __syncthreads();   // B2: hA(t+1) complete
    }
}

// ----------------------------------------------------- head (unchanged)
__global__ __launch_bounds__(256) void k_head(
    const float* __restrict__ h_f, const float* __restrict__ h_b,
    const float* __restrict__ Wc, const float* __restrict__ bc,
    float* __restrict__ out)
{
    __shared__ float pool[512];
    const int b = blockIdx.x, tid = threadIdx.x;
    float p0 = fmaxf(h_f[(size_t)b*LHID + tid], 0.f);
    float p1 = fmaxf(h_b[(size_t)b*LHID + tid], 0.f);
    pool[tid] = p0; pool[256 + tid] = p1;
    out[(size_t)b*512 + tid]       = p0;
    out[(size_t)b*512 + 256 + tid] = p1;
    __syncthreads();
    for (int n = tid; n < NCLS; n += 256){
        float a = bc[n];
        const float* ww = Wc + (size_t)n * 512;
        #pragma unroll 4
        for (int k = 0; k < 512; k += 4){
            float4 wv = *(const float4*)(ww + k);
            a += pool[k]*wv.x + pool[k+1]*wv.y + pool[k+2]*wv.z + pool[k+3]*wv.w;
        }
        out[(size_t)BB*512 + (size_t)b*NCLS + n] = a;
    }
}

// ---------------------------------------------------------------------------
extern "C" void kernel_launch(void* const* d_in, const int* in_sizes, int n_in,
                              void* d_out, int out_size, void* d_ws, size_t ws_size,
                              hipStream_t stream) {
    const float* pose1 = (const float*)d_in[0];
    const float* pose2 = (const float*)d_in[1];
    const float* W1    = (const float*)d_in[2];
    const float* b1    = (const float*)d_in[3];
    const float* W2    = (const float*)d_in[4];
    const float* b2    = (const float*)d_in[5];
    const float* Wih_f = (const float*)d_in[6];
    const float* Whh_f = (const float*)d_in[7];
    const float* bih_f = (const float*)d_in[8];
    const float* bhh_f = (const float*)d_in[9];
    const float* Wih_b = (const float*)d_in[10];
    const float* bih_b = (const float*)d_in[12];
    const float* bhh_b = (const float*)d_in[13];
    const float* Wc    = (const float*)d_in[14];
    const float* bc    = (const float*)d_in[15];
    (void)in_sizes; (void)n_in; (void)out_size; (void)ws_size;
    float* out = (float*)d_out;
    char* ws = (char*)d_ws;

    // workspace (within the 211,812,352-byte footprint used since R1)
    u16t*           WTfrag = (u16t*)(ws + 0);                     // 524,288
    __hip_bfloat16* W2Tb   = (__hip_bfloat16*)(ws + 524288);      //  32,768
    int*            flags  = (int*)(ws + 557056);                 //   2,048
    unsigned*       hx     = (unsigned*)(ws + 589824);            // 262,144
    float*          h_b    = (float*)(ws + 851968);               // 131,072
    float*          h_f    = (float*)(ws + 983040);               // 131,072
    __hip_bfloat16* feats  = (__hip_bfloat16*)(ws + 2097152);     // 142,606,336
    u16t*           pre2   = (u16t*)(ws + 144703488);             //  67,108,864

    k_zeroflags<<<1, 512, 0, stream>>>(flags);
    k_w2t     <<<64, 256, 0, stream>>>(W2, W2Tb);
    k_wfrag   <<<128, 256, 0, stream>>>(Whh_f, WTfrag);
    k_gcnfused<<<2048, 512, 0, stream>>>(pose1, pose2, W1, b1, b2, W2Tb, feats);
    k_gemm_mfma<<<dim3(256, 8), 256, 0, stream>>>(feats, Wih_f, bih_f, bhh_f, pre2);
    k_lstm_b  <<<dim3(128, 64), 256, 0, stream>>>(feats + (size_t)255*BB*DD, Wih_b, bih_b, bhh_b, h_b);
    k_lstm_f6 <<<32, 512, 0, stream>>>(pre2, WTfrag, hx, flags, h_f);
    k_head    <<<128, 256, 0, stream>>>(h_f, h_b, Wc, bc, out);
}

// Round 8
// 1995.963 us; speedup vs baseline: 1.8093x; 1.8093x over previous
//
#include <hip/hip_runtime.h>
#include <hip/hip_bf16.h>

// ---------------------------------------------------------------------------
// PoseFeatureNet R8:
//  - k_lstm_f7: fully CU-local recurrence. 8 WGs x 16 samples, 1024 threads
//    (16 waves). Wave owns 16 j x 4 gates (nt=gate), full K=256. Whh frags:
//    kc0-5 VGPR-resident (96 VGPR), kc6-7 LDS-resident (128 KB). NO per-step
//    Whh stream, NO inter-WG exchange, NO flags. hA single-buffered in LDS,
//    2 barriers/step. Layouts identical to R5 (wfrag + gemm epilogue reverted
//    to R5) -> clean A/B isolating the Whh L2 stream.
//  - k_gcnfused / k_lstm_b / k_head unchanged.
// ---------------------------------------------------------------------------

#define TT 256
#define BB 128
#define NNODE 17
#define DD 2176    // 17*128
#define LHID 256
#define G4 1024    // 4*LHID
#define NCLS 625

typedef unsigned short u16t;

__device__ __constant__ int ESRC[19] = {15,13,16,14,11,5,6,5,5,6,7,8,1,0,0,1,2,3,4};
__device__ __constant__ int EDST[19] = {13,11,14,12,12,11,12,6,7,8,9,10,2,1,2,3,4,5,6};
__device__ __constant__ float DEGF[17] = {1,2,3,2,2,2,3,2,2,2,2,3,4,2,2,1,1};

__device__ inline float lo2f(unsigned u){ union{unsigned x; float f;} c; c.x = u << 16; return c.f; }
__device__ inline float hi2f(unsigned u){ union{unsigned x; float f;} c; c.x = u & 0xffff0000u; return c.f; }
__device__ inline u16t f2b(float f){
    __hip_bfloat16 h = __float2bfloat16(f);
    u16t s; __builtin_memcpy(&s, &h, 2); return s;
}
__device__ inline float b2f(u16t s){ union{unsigned x; float f;} c; c.x = ((unsigned)s) << 16; return c.f; }
__device__ inline unsigned pack2(float a, float b){
    return (unsigned)f2b(a) | ((unsigned)f2b(b) << 16);
}
__device__ inline float fsig(float x){ return __fdividef(1.f, 1.f + __expf(-x)); }
__device__ inline float ftanh(float x){ float e = __expf(2.f*x); return 1.f - __fdividef(2.f, e + 1.f); }
__device__ inline float sigm(float x){ return 1.f / (1.f + expf(-x)); }

typedef __attribute__((ext_vector_type(8))) short bf16x8;
typedef __attribute__((ext_vector_type(4))) float f32x4;

__device__ inline void gload16(const void* g, void* l){
    __builtin_amdgcn_global_load_lds(
        (const __attribute__((address_space(1))) void*)g,
        (__attribute__((address_space(3))) void*)l, 16, 0, 0);
}

// --------------------------------------------- W2 -> bf16 transposed [n][k]
__global__ void k_w2t(const float* __restrict__ W2, __hip_bfloat16* __restrict__ W2Tb){
    int g = blockIdx.x * 256 + threadIdx.x;   // 16384
    int k = g >> 7, n = g & 127;
    W2Tb[n * 128 + k] = __float2bfloat16(W2[g]);
}

// ------------------- Whh -> bf16 fragments, R5 packing (16 waves, nt = gate)
// frag f = w*32 + kc*4 + nt  (w:16 waves, kc:8, nt:4 gates)
// lane l holds B[k = kc*32 + (l>>4)*8 ..+8][col = nt*256 + w*16 + (l&15)]
__global__ void k_wfrag(const float* __restrict__ Whh, __hip_bfloat16* __restrict__ WTfrag){
    int g = blockIdx.x * 256 + threadIdx.x;   // 32768
    int f = g >> 6, lane = g & 63;
    int w = f >> 5, kc = (f >> 2) & 7, nt = f & 3;
    int col = nt*256 + w*16 + (lane & 15);
    int k0  = kc*32 + (lane >> 4)*8;
    const float* src = Whh + (size_t)col * 256 + k0;
    float4 f0 = *(const float4*)src;
    float4 f1 = *(const float4*)(src + 4);
    uint4 o;
    o.x = pack2(f0.x, f0.y); o.y = pack2(f0.z, f0.w);
    o.z = pack2(f1.x, f1.y); o.w = pack2(f1.z, f1.w);
    *(uint4*)((char*)WTfrag + (size_t)g * 16) = o;
}

// ------------------------------------------------------------ fused GCN block
__global__ __launch_bounds__(512) void k_gcnfused(
    const float* __restrict__ pose1, const float* __restrict__ pose2,
    const float* __restrict__ W1, const float* __restrict__ b1,
    const float* __restrict__ b2, const __hip_bfloat16* __restrict__ W2Tb,
    __hip_bfloat16* __restrict__ feats)
{
    __shared__ u16t  Abuf[272][136];
    __shared__ u16t  BsmT[128][136];
    __shared__ float ps4[2][16][17][4];
    __shared__ float araw[17*128];
    __shared__ float araw2[17*128];
    __shared__ float As[289];

    const int tid = threadIdx.x;
    const int blk = blockIdx.x;
    const int t   = blk >> 3;
    const int bc  = blk & 7;

    for (int idx = tid; idx < 1632; idx += 512){
        int p_ = idx >= 816 ? 1 : 0;
        int r  = idx - p_ * 816;
        int bl = r / 51, i = r - bl * 51;
        int n = i / 3, c = i - n * 3;
        const float* src = p_ ? pose2 : pose1;
        ps4[p_][bl][n][c] = src[(size_t)((bc*16 + bl) * TT + t) * 51 + i];
    }
    {
        const uint4* src = (const uint4*)W2Tb;
        for (int r = 0; r < 2; ++r){
            int f0 = (tid + r * 512) * 16;
            int n = f0 >> 7, k0 = f0 & 127;
            uint4 v0 = src[(tid + r*512)*2 + 0];
            uint4 v1 = src[(tid + r*512)*2 + 1];
            *(uint4*)&BsmT[n][k0]     = v0;
            *(uint4*)&BsmT[n][k0 + 8] = v1;
        }
    }
    if (bc == 0 && tid < 289){
        int i = tid / 17, j = tid - (tid/17)*17;
        float a = (i == j) ? 1.0f / DEGF[i] : 0.0f;
        for (int e = 0; e < 19; ++e)
            if (EDST[e] == i && ESRC[e] == j)
                a += 1.0f / sqrtf(DEGF[i] * DEGF[j]);
        As[tid] = a;
    }

    const int h = tid & 127;
    const int q = tid >> 7;
    const float w10 = W1[h], w11 = W1[128 + h], w12 = W1[256 + h];
    const float b1h = b1[h];
    __syncthreads();

    float a2st[5];
    int nl[5], nv = 0;
    for (int s = 0; s < 5; ++s){ int n = q + 4*s; if (n < NNODE) nl[nv++] = n; }
    for (int s = 0; s < nv; ++s){
        int n = nl[s];
        for (int bl = 0; bl < 16; ++bl){
            float4 p1 = *(const float4*)&ps4[0][bl][n][0];
            float4 p2 = *(const float4*)&ps4[1][bl][n][0];
            float a1 = p1.x*w10 + p1.y*w11 + p1.z*w12;
            float a2 = p2.x*w10 + p2.y*w11 + p2.z*w12;
            if (bc == 0 && bl == 0){
                araw[n*128 + h] = a1;
                a2st[s] = a2;
            } else {
                float r1 = fmaxf(a1 + b1h, 0.f);
                float r2 = fmaxf(a2 + b1h, 0.f);
                Abuf[n*16 + bl][h] = f2b(0.5f*(r1 + r2));
            }
        }
    }
    __syncthreads();
    if (bc == 0){
        for (int s = 0; s < nv; ++s){
            int n = nl[s]; float a = 0.f;
            #pragma unroll
            for (int j = 0; j < NNODE; ++j) a += As[n*17 + j] * araw[j*128 + h];
            araw2[n*128 + h] = fmaxf(a + b1h, 0.f);
        }
    }
    __syncthreads();
    if (bc == 0){
        for (int s = 0; s < nv; ++s){
            int n = nl[s]; float a = 0.f;
            #pragma unroll
            for (int j = 0; j < NNODE; ++j) a += As[n*17 + j] * araw2[j*128 + h];
            float r2 = fmaxf(a2st[s] + b1h, 0.f);
            Abuf[n*16 + 0][h] = f2b(0.5f*(a + r2));
        }
    }
    __syncthreads();

    const int w = tid >> 6, l = tid & 63;
    const int l15 = l & 15, q8 = (l >> 4) * 8, q4 = (l >> 4) * 4;
    float bias[8];
    #pragma unroll
    for (int nt = 0; nt < 8; ++nt) bias[nt] = b2[nt*16 + l15];

    bf16x8 Bf[4][8];
    #pragma unroll
    for (int kc = 0; kc < 4; ++kc)
        #pragma unroll
        for (int nt = 0; nt < 8; ++nt)
            Bf[kc][nt] = *(const bf16x8*)&BsmT[nt*16 + l15][kc*32 + q8];

    u16t* Cb = (u16t*)feats;
    for (int mt = w; mt < NNODE; mt += 8){
        f32x4 acc[8];
        #pragma unroll
        for (int nt = 0; nt < 8; ++nt) acc[nt] = (f32x4){0.f,0.f,0.f,0.f};
        #pragma unroll
        for (int kc = 0; kc < 4; ++kc){
            bf16x8 a = *(const bf16x8*)&Abuf[mt*16 + l15][kc*32 + q8];
            #pragma unroll
            for (int nt = 0; nt < 8; ++nt)
                acc[nt] = __builtin_amdgcn_mfma_f32_16x16x32_bf16(a, Bf[kc][nt], acc[nt], 0,0,0);
        }
        #pragma unroll
        for (int nt = 0; nt < 8; ++nt)
            #pragma unroll
            for (int r = 0; r < 4; ++r){
                size_t row = (size_t)(blk*16 + q4 + r) * NNODE + mt;
                Cb[row*128 + nt*16 + l15] = f2b(acc[nt][r] + bias[nt]);
            }
    }
}

// ------------------------------------------------- pre_f GEMM: bf16 MFMA
// R5 epilogue layout:
// off = t*131072 + (b>>4)*16384 + (j>>4)*1024 + ((b&15)>>2)*256 + (b&3)*64
//       + (j&15)*4 + gate      where col = gate*256 + j
__global__ __launch_bounds__(256) void k_gemm_mfma(
    const __hip_bfloat16* __restrict__ A, const float* __restrict__ Bw,
    const float* __restrict__ bi1, const float* __restrict__ bi2,
    u16t* __restrict__ pre2)
{
    __shared__ u16t Asm[128][32];
    __shared__ u16t Bsm[128][32];
    const int tid = threadIdx.x;
    const int w = tid >> 6;
    const int l = tid & 63;
    const size_t m0 = (size_t)blockIdx.x * 128;
    const int n0 = blockIdx.y * 128;
    const int mw = (w >> 1) * 64;
    const int nw = (w & 1) * 64;

    f32x4 acc[4][4];
    #pragma unroll
    for (int s = 0; s < 4; ++s)
        #pragma unroll
        for (int t_ = 0; t_ < 4; ++t_)
            acc[s][t_] = (f32x4){0.f, 0.f, 0.f, 0.f};

    const u16t* Ab = (const u16t*)A;
    const int arow = w*32 + (l>>2);
    const int akoff = (l&3)*8;
    const int brow = w*32 + (l>>1);
    const int bko  = (l&1)*16;
    const int fr = l & 15, fq = (l >> 4) * 8;

    for (int kt = 0; kt < DD; kt += 32){
        gload16(Ab + (m0 + arow)*DD + kt + akoff,      &Asm[arow][akoff]);
        gload16(Ab + (m0 + arow + 16)*DD + kt + akoff, &Asm[arow+16][akoff]);
        const float* bp = Bw + (size_t)(n0 + brow)*DD + kt + bko;
        float4 f0 = *(const float4*)bp;
        float4 f1 = *(const float4*)(bp+4);
        float4 f2 = *(const float4*)(bp+8);
        float4 f3 = *(const float4*)(bp+12);
        uint4 o0, o1;
        o0.x = pack2(f0.x,f0.y); o0.y = pack2(f0.z,f0.w);
        o0.z = pack2(f1.x,f1.y); o0.w = pack2(f1.z,f1.w);
        o1.x = pack2(f2.x,f2.y); o1.y = pack2(f2.z,f2.w);
        o1.z = pack2(f3.x,f3.y); o1.w = pack2(f3.z,f3.w);
        *(uint4*)&Bsm[brow][bko]   = o0;
        *(uint4*)&Bsm[brow][bko+8] = o1;
        __syncthreads();

        bf16x8 af[4], bf[4];
        #pragma unroll
        for (int s = 0; s < 4; ++s) af[s] = *(const bf16x8*)&Asm[mw + s*16 + fr][fq];
        #pragma unroll
        for (int t_ = 0; t_ < 4; ++t_) bf[t_] = *(const bf16x8*)&Bsm[nw + t_*16 + fr][fq];
        #pragma unroll
        for (int s = 0; s < 4; ++s)
            #pragma unroll
            for (int t_ = 0; t_ < 4; ++t_)
                acc[s][t_] = __builtin_amdgcn_mfma_f32_16x16x32_bf16(af[s], bf[t_], acc[s][t_], 0, 0, 0);
        __syncthreads();
    }

    const int cr = (l >> 4) * 4;
    const int cc = l & 15;
    const int tIdx = blockIdx.x;   // rows are t-major: row = t*128 + b
    #pragma unroll
    for (int t_ = 0; t_ < 4; ++t_){
        int col = n0 + nw + t_*16 + cc;
        float bias = bi1[col] + bi2[col];
        int gate = col >> 8;
        int j    = col & 255;
        size_t cbase = (size_t)tIdx*131072 + (size_t)(j>>4)*1024 + (size_t)(j&15)*4 + gate;
        #pragma unroll
        for (int s = 0; s < 4; ++s)
            #pragma unroll
            for (int r = 0; r < 4; ++r){
                int b = mw + s*16 + cr + r;
                pre2[cbase + (size_t)(b>>4)*16384 + ((b&15)>>2)*256 + (b&3)*64]
                    = f2b(acc[s][t_][r] + bias);
            }
    }
}

// --------------------- backward LSTM: one step from zero state (unchanged)
__global__ __launch_bounds__(256) void k_lstm_b(
    const __hip_bfloat16* __restrict__ feats255,
    const float* __restrict__ Wih_b,
    const float* __restrict__ bih_b, const float* __restrict__ bhh_b,
    float* __restrict__ h_b)
{
    __shared__ float fs[DD];
    const int tid = threadIdx.x;
    const int b = blockIdx.x;
    const unsigned* fbu = (const unsigned*)(feats255 + (size_t)b * DD);
    for (int i = tid; i < DD/2; i += 256){
        unsigned u = fbu[i];
        fs[2*i] = lo2f(u); fs[2*i+1] = hi2f(u);
    }
    __syncthreads();

    const int w = tid >> 6, lane = tid & 63;
    const int j = blockIdx.y * 4 + w;
    const float* Wi = Wih_b + (size_t)j * DD;
    const float* Wg = Wih_b + (size_t)(512 + j) * DD;
    const float* Wo = Wih_b + (size_t)(768 + j) * DD;
    float si = 0.f, sg = 0.f, so = 0.f;
    #pragma unroll 2
    for (int i = 0; i < 34; ++i){
        int k = lane + i*64;
        float f = fs[k];
        si += f * Wi[k]; sg += f * Wg[k]; so += f * Wo[k];
    }
    #pragma unroll
    for (int off = 32; off > 0; off >>= 1){
        si += __shfl_down(si, off);
        sg += __shfl_down(sg, off);
        so += __shfl_down(so, off);
    }
    if (lane == 0){
        float zi = si + bih_b[j]       + bhh_b[j];
        float zg = sg + bih_b[512 + j] + bhh_b[512 + j];
        float zo = so + bih_b[768 + j] + bhh_b[768 + j];
        float c = sigm(zi) * tanhf(zg);
        h_b[(size_t)b*LHID + j] = sigm(zo) * tanhf(c);
    }
}

// ------------- forward LSTM R8: fully CU-local, Whh resident (VGPR+LDS)
// 8 WGs x 16 samples, 1024 threads (16 waves). Wave w owns j in
// [w*16, w*16+16) x 4 gates (nt=gate), full K=256. kc0-5 frags in VGPR,
// kc6-7 frags in LDS. No streaming, no exchange. 2 barriers/step.
__global__ __launch_bounds__(1024, 4) void k_lstm_f7(
    const u16t* __restrict__ pre2,            // R5 permuted layout
    const __hip_bfloat16* __restrict__ WTfrag,
    float* __restrict__ hout)                 // (128,256)
{
    __shared__ u16t Wl[65536];       // 128 KB: kc6-7 frags, [w][fi][lane][8]
    __shared__ u16t hAhi[16][264];   // 8.25 KB
    __shared__ u16t hAlo[16][264];

    const int tid = threadIdx.x;
    const int w = tid >> 6, l = tid & 63;
    const int q = l >> 4, l15 = l & 15, q8 = q * 8;
    const int j = w*16 + l15;
    const int wg = blockIdx.x;
    const u16t* wtf = (const u16t*)WTfrag;

    // stage kc6-7 fragments into LDS (8 frags/wave x 16 waves = 128 KB)
    {
        const uint4* srcq = (const uint4*)wtf;
        uint4* dstq = (uint4*)Wl;
        for (int i = tid; i < 8192; i += 1024){
            int iw = i >> 9, fi = (i >> 6) & 7, il = i & 63;
            dstq[i] = srcq[(iw*32 + 24 + fi)*64 + il];
        }
    }
    for (int i = tid; i < 16*264; i += 1024){
        ((u16t*)hAhi)[i] = 0; ((u16t*)hAlo)[i] = 0;
    }

    // resident kc0-5 fragments: 24 frags = 96 VGPR
    bf16x8 Bv[6][4];
    #pragma unroll
    for (int kc = 0; kc < 6; ++kc)
        #pragma unroll
        for (int nt = 0; nt < 4; ++nt)
            Bv[kc][nt] = *(const bf16x8*)(wtf + (((size_t)(w*32 + kc*4 + nt))*64 + l)*8);

    float cst[4] = {0.f, 0.f, 0.f, 0.f};
    // pre2 lane base: wg*16384 + w*1024 + q*256 + r*64 + l15*4 (+ gate)
    const size_t pbase = (size_t)wg*16384 + (size_t)w*1024 + (size_t)q*256 + (size_t)l15*4;
    __syncthreads();

    #pragma unroll 1
    for (int t = 0; t < TT; ++t){
        f32x4 acc[4];
        #pragma unroll
        for (int nt = 0; nt < 4; ++nt) acc[nt] = (f32x4){0.f,0.f,0.f,0.f};

        #pragma unroll
        for (int kc = 0; kc < 6; ++kc){
            bf16x8 ah = *(const bf16x8*)&hAhi[l15][kc*32 + q8];
            bf16x8 al = *(const bf16x8*)&hAlo[l15][kc*32 + q8];
            #pragma unroll
            for (int nt = 0; nt < 4; ++nt)
                acc[nt] = __builtin_amdgcn_mfma_f32_16x16x32_bf16(ah, Bv[kc][nt], acc[nt], 0,0,0);
            #pragma unroll
            for (int nt = 0; nt < 4; ++nt)
                acc[nt] = __builtin_amdgcn_mfma_f32_16x16x32_bf16(al, Bv[kc][nt], acc[nt], 0,0,0);
        }
        #pragma unroll
        for (int kc = 6; kc < 8; ++kc){
            bf16x8 ah = *(const bf16x8*)&hAhi[l15][kc*32 + q8];
            bf16x8 al = *(const bf16x8*)&hAlo[l15][kc*32 + q8];
            #pragma unroll
            for (int nt = 0; nt < 4; ++nt){
                bf16x8 bL = *(const bf16x8*)&Wl[((w*8 + (kc-6)*4 + nt)*64 + l)*8];
                acc[nt] = __builtin_amdgcn_mfma_f32_16x16x32_bf16(ah, bL, acc[nt], 0,0,0);
                acc[nt] = __builtin_amdgcn_mfma_f32_16x16x32_bf16(al, bL, acc[nt], 0,0,0);
            }
        }

        // gates (pre loaded late to keep live range short)
        union { uint2 v; u16t s4[4]; } pr[4];
        {
            const u16t* pp = pre2 + (size_t)t*131072 + pbase;
            #pragma unroll
            for (int r = 0; r < 4; ++r) pr[r].v = *(const uint2*)(pp + r*64);
        }
        float hhv[4]; u16t hb[4], lb[4];
        #pragma unroll
        for (int r = 0; r < 4; ++r){
            float zi = acc[0][r] + b2f(pr[r].s4[0]);
            float zf = acc[1][r] + b2f(pr[r].s4[1]);
            float zg = acc[2][r] + b2f(pr[r].s4[2]);
            float zo = acc[3][r] + b2f(pr[r].s4[3]);
            float cn = fsig(zf)*cst[r] + fsig(zi)*ftanh(zg);
            cst[r] = cn;
            hhv[r] = fsig(zo)*ftanh(cn);
            hb[r] = f2b(hhv[r]);
            lb[r] = f2b(hhv[r] - b2f(hb[r]));
        }

        __syncthreads();   // B1: all MFMA reads of hA(t) complete

        if (t < TT - 1){
            #pragma unroll
            for (int r = 0; r < 4; ++r){
                const int s = q*4 + r;
                hAhi[s][j] = hb[r];
                hAlo[s][j] = lb[r];
            }
        } else {
            #pragma unroll
            for (int r = 0; r < 4; ++r)
                hout[((size_t)wg*16 + q*4 + r)*LHID + j] = hhv[r];
        }
        __syncthreads();   // B2: hA(t+1) complete
    }
}

// ----------------------------------------------------- head (unchanged)
__global__ __launch_bounds__(256) void k_head(
    const float* __restrict__ h_f, const float* __restrict__ h_b,
    const float* __restrict__ Wc, const float* __restrict__ bc,
    float* __restrict__ out)
{
    __shared__ float pool[512];
    const int b = blockIdx.x, tid = threadIdx.x;
    float p0 = fmaxf(h_f[(size_t)b*LHID + tid], 0.f);
    float p1 = fmaxf(h_b[(size_t)b*LHID + tid], 0.f);
    pool[tid] = p0; pool[256 + tid] = p1;
    out[(size_t)b*512 + tid]       = p0;
    out[(size_t)b*512 + 256 + tid] = p1;
    __syncthreads();
    for (int n = tid; n < NCLS; n += 256){
        float a = bc[n];
        const float* ww = Wc + (size_t)n * 512;
        #pragma unroll 4
        for (int k = 0; k < 512; k += 4){
            float4 wv = *(const float4*)(ww + k);
            a += pool[k]*wv.x + pool[k+1]*wv.y + pool[k+2]*wv.z + pool[k+3]*wv.w;
        }
        out[(size_t)BB*512 + (size_t)b*NCLS + n] = a;
    }
}

// ---------------------------------------------------------------------------
extern "C" void kernel_launch(void* const* d_in, const int* in_sizes, int n_in,
                              void* d_out, int out_size, void* d_ws, size_t ws_size,
                              hipStream_t stream) {
    const float* pose1 = (const float*)d_in[0];
    const float* pose2 = (const float*)d_in[1];
    const float* W1    = (const float*)d_in[2];
    const float* b1    = (const float*)d_in[3];
    const float* W2    = (const float*)d_in[4];
    const float* b2    = (const float*)d_in[5];
    const float* Wih_f = (const float*)d_in[6];
    const float* Whh_f = (const float*)d_in[7];
    const float* bih_f = (const float*)d_in[8];
    const float* bhh_f = (const float*)d_in[9];
    const float* Wih_b = (const float*)d_in[10];
    const float* bih_b = (const float*)d_in[12];
    const float* bhh_b = (const float*)d_in[13];
    const float* Wc    = (const float*)d_in[14];
    const float* bc    = (const float*)d_in[15];
    (void)in_sizes; (void)n_in; (void)out_size; (void)ws_size;
    float* out = (float*)d_out;
    char* ws = (char*)d_ws;

    // workspace (same 211,812,352-byte footprint)
    __hip_bfloat16* WTfrag = (__hip_bfloat16*)(ws + 0);           // 524,288
    __hip_bfloat16* W2Tb   = (__hip_bfloat16*)(ws + 524288);      //  32,768
    float*          h_b    = (float*)(ws + 557056);               // 131,072
    float*          h_f    = (float*)(ws + 688128);               // 131,072
    __hip_bfloat16* feats  = (__hip_bfloat16*)(ws + 2097152);     // 142,606,336
    u16t*           pre2   = (u16t*)(ws + 144703488);             //  67,108,864

    k_w2t     <<<64, 256, 0, stream>>>(W2, W2Tb);
    k_wfrag   <<<128, 256, 0, stream>>>(Whh_f, WTfrag);
    k_gcnfused<<<2048, 512, 0, stream>>>(pose1, pose2, W1, b1, b2, W2Tb, feats);
    k_gemm_mfma<<<dim3(256, 8), 256, 0, stream>>>(feats, Wih_f, bih_f, bhh_f, pre2);
    k_lstm_b  <<<dim3(128, 64), 256, 0, stream>>>(feats + (size_t)255*BB*DD, Wih_b, bih_b, bhh_b, h_b);
    k_lstm_f7 <<<8, 1024, 0, stream>>>(pre2, WTfrag, h_f);
    k_head    <<<128, 256, 0, stream>>>(h_f, h_b, Wc, bc, out);
}

// Round 9
// 1758.505 us; speedup vs baseline: 2.0536x; 1.1350x over previous
//
#include <hip/hip_runtime.h>
#include <hip/hip_bf16.h>

// ---------------------------------------------------------------------------
// PoseFeatureNet R9:
//  - k_lstm_f8: CU-local recurrence (R8 structure) with
//      * h stored bf16 single (lo-correction dropped): MFMA 64->32/wave,
//        hA LDS reads halved
//      * hA double-buffered -> ONE barrier/step
//      * pre2 load hoisted to start of step (hidden under MFMA)
//    Whh: kc0-5 VGPR-resident (96 VGPR), kc6-7 LDS (128 KB). No streaming,
//    no inter-WG traffic.
//  - everything else unchanged from R8.
// ---------------------------------------------------------------------------

#define TT 256
#define BB 128
#define NNODE 17
#define DD 2176    // 17*128
#define LHID 256
#define G4 1024    // 4*LHID
#define NCLS 625

typedef unsigned short u16t;

__device__ __constant__ int ESRC[19] = {15,13,16,14,11,5,6,5,5,6,7,8,1,0,0,1,2,3,4};
__device__ __constant__ int EDST[19] = {13,11,14,12,12,11,12,6,7,8,9,10,2,1,2,3,4,5,6};
__device__ __constant__ float DEGF[17] = {1,2,3,2,2,2,3,2,2,2,2,3,4,2,2,1,1};

__device__ inline float lo2f(unsigned u){ union{unsigned x; float f;} c; c.x = u << 16; return c.f; }
__device__ inline float hi2f(unsigned u){ union{unsigned x; float f;} c; c.x = u & 0xffff0000u; return c.f; }
__device__ inline u16t f2b(float f){
    __hip_bfloat16 h = __float2bfloat16(f);
    u16t s; __builtin_memcpy(&s, &h, 2); return s;
}
__device__ inline float b2f(u16t s){ union{unsigned x; float f;} c; c.x = ((unsigned)s) << 16; return c.f; }
__device__ inline unsigned pack2(float a, float b){
    return (unsigned)f2b(a) | ((unsigned)f2b(b) << 16);
}
__device__ inline float fsig(float x){ return __fdividef(1.f, 1.f + __expf(-x)); }
__device__ inline float ftanh(float x){ float e = __expf(2.f*x); return 1.f - __fdividef(2.f, e + 1.f); }
__device__ inline float sigm(float x){ return 1.f / (1.f + expf(-x)); }

typedef __attribute__((ext_vector_type(8))) short bf16x8;
typedef __attribute__((ext_vector_type(4))) float f32x4;

__device__ inline void gload16(const void* g, void* l){
    __builtin_amdgcn_global_load_lds(
        (const __attribute__((address_space(1))) void*)g,
        (__attribute__((address_space(3))) void*)l, 16, 0, 0);
}

// --------------------------------------------- W2 -> bf16 transposed [n][k]
__global__ void k_w2t(const float* __restrict__ W2, __hip_bfloat16* __restrict__ W2Tb){
    int g = blockIdx.x * 256 + threadIdx.x;   // 16384
    int k = g >> 7, n = g & 127;
    W2Tb[n * 128 + k] = __float2bfloat16(W2[g]);
}

// ------------------- Whh -> bf16 fragments, R5 packing (16 waves, nt = gate)
// frag f = w*32 + kc*4 + nt  (w:16 waves, kc:8, nt:4 gates)
// lane l holds B[k = kc*32 + (l>>4)*8 ..+8][col = nt*256 + w*16 + (l&15)]
__global__ void k_wfrag(const float* __restrict__ Whh, __hip_bfloat16* __restrict__ WTfrag){
    int g = blockIdx.x * 256 + threadIdx.x;   // 32768
    int f = g >> 6, lane = g & 63;
    int w = f >> 5, kc = (f >> 2) & 7, nt = f & 3;
    int col = nt*256 + w*16 + (lane & 15);
    int k0  = kc*32 + (lane >> 4)*8;
    const float* src = Whh + (size_t)col * 256 + k0;
    float4 f0 = *(const float4*)src;
    float4 f1 = *(const float4*)(src + 4);
    uint4 o;
    o.x = pack2(f0.x, f0.y); o.y = pack2(f0.z, f0.w);
    o.z = pack2(f1.x, f1.y); o.w = pack2(f1.z, f1.w);
    *(uint4*)((char*)WTfrag + (size_t)g * 16) = o;
}

// ------------------------------------------------------------ fused GCN block
__global__ __launch_bounds__(512) void k_gcnfused(
    const float* __restrict__ pose1, const float* __restrict__ pose2,
    const float* __restrict__ W1, const float* __restrict__ b1,
    const float* __restrict__ b2, const __hip_bfloat16* __restrict__ W2Tb,
    __hip_bfloat16* __restrict__ feats)
{
    __shared__ u16t  Abuf[272][136];
    __shared__ u16t  BsmT[128][136];
    __shared__ float ps4[2][16][17][4];
    __shared__ float araw[17*128];
    __shared__ float araw2[17*128];
    __shared__ float As[289];

    const int tid = threadIdx.x;
    const int blk = blockIdx.x;
    const int t   = blk >> 3;
    const int bc  = blk & 7;

    for (int idx = tid; idx < 1632; idx += 512){
        int p_ = idx >= 816 ? 1 : 0;
        int r  = idx - p_ * 816;
        int bl = r / 51, i = r - bl * 51;
        int n = i / 3, c = i - n * 3;
        const float* src = p_ ? pose2 : pose1;
        ps4[p_][bl][n][c] = src[(size_t)((bc*16 + bl) * TT + t) * 51 + i];
    }
    {
        const uint4* src = (const uint4*)W2Tb;
        for (int r = 0; r < 2; ++r){
            int f0 = (tid + r * 512) * 16;
            int n = f0 >> 7, k0 = f0 & 127;
            uint4 v0 = src[(tid + r*512)*2 + 0];
            uint4 v1 = src[(tid + r*512)*2 + 1];
            *(uint4*)&BsmT[n][k0]     = v0;
            *(uint4*)&BsmT[n][k0 + 8] = v1;
        }
    }
    if (bc == 0 && tid < 289){
        int i = tid / 17, j = tid - (tid/17)*17;
        float a = (i == j) ? 1.0f / DEGF[i] : 0.0f;
        for (int e = 0; e < 19; ++e)
            if (EDST[e] == i && ESRC[e] == j)
                a += 1.0f / sqrtf(DEGF[i] * DEGF[j]);
        As[tid] = a;
    }

    const int h = tid & 127;
    const int q = tid >> 7;
    const float w10 = W1[h], w11 = W1[128 + h], w12 = W1[256 + h];
    const float b1h = b1[h];
    __syncthreads();

    float a2st[5];
    int nl[5], nv = 0;
    for (int s = 0; s < 5; ++s){ int n = q + 4*s; if (n < NNODE) nl[nv++] = n; }
    for (int s = 0; s < nv; ++s){
        int n = nl[s];
        for (int bl = 0; bl < 16; ++bl){
            float4 p1 = *(const float4*)&ps4[0][bl][n][0];
            float4 p2 = *(const float4*)&ps4[1][bl][n][0];
            float a1 = p1.x*w10 + p1.y*w11 + p1.z*w12;
            float a2 = p2.x*w10 + p2.y*w11 + p2.z*w12;
            if (bc == 0 && bl == 0){
                araw[n*128 + h] = a1;
                a2st[s] = a2;
            } else {
                float r1 = fmaxf(a1 + b1h, 0.f);
                float r2 = fmaxf(a2 + b1h, 0.f);
                Abuf[n*16 + bl][h] = f2b(0.5f*(r1 + r2));
            }
        }
    }
    __syncthreads();
    if (bc == 0){
        for (int s = 0; s < nv; ++s){
            int n = nl[s]; float a = 0.f;
            #pragma unroll
            for (int j = 0; j < NNODE; ++j) a += As[n*17 + j] * araw[j*128 + h];
            araw2[n*128 + h] = fmaxf(a + b1h, 0.f);
        }
    }
    __syncthreads();
    if (bc == 0){
        for (int s = 0; s < nv; ++s){
            int n = nl[s]; float a = 0.f;
            #pragma unroll
            for (int j = 0; j < NNODE; ++j) a += As[n*17 + j] * araw2[j*128 + h];
            float r2 = fmaxf(a2st[s] + b1h, 0.f);
            Abuf[n*16 + 0][h] = f2b(0.5f*(a + r2));
        }
    }
    __syncthreads();

    const int w = tid >> 6, l = tid & 63;
    const int l15 = l & 15, q8 = (l >> 4) * 8, q4 = (l >> 4) * 4;
    float bias[8];
    #pragma unroll
    for (int nt = 0; nt < 8; ++nt) bias[nt] = b2[nt*16 + l15];

    bf16x8 Bf[4][8];
    #pragma unroll
    for (int kc = 0; kc < 4; ++kc)
        #pragma unroll
        for (int nt = 0; nt < 8; ++nt)
            Bf[kc][nt] = *(const bf16x8*)&BsmT[nt*16 + l15][kc*32 + q8];

    u16t* Cb = (u16t*)feats;
    for (int mt = w; mt < NNODE; mt += 8){
        f32x4 acc[8];
        #pragma unroll
        for (int nt = 0; nt < 8; ++nt) acc[nt] = (f32x4){0.f,0.f,0.f,0.f};
        #pragma unroll
        for (int kc = 0; kc < 4; ++kc){
            bf16x8 a = *(const bf16x8*)&Abuf[mt*16 + l15][kc*32 + q8];
            #pragma unroll
            for (int nt = 0; nt < 8; ++nt)
                acc[nt] = __builtin_amdgcn_mfma_f32_16x16x32_bf16(a, Bf[kc][nt], acc[nt], 0,0,0);
        }
        #pragma unroll
        for (int nt = 0; nt < 8; ++nt)
            #pragma unroll
            for (int r = 0; r < 4; ++r){
                size_t row = (size_t)(blk*16 + q4 + r) * NNODE + mt;
                Cb[row*128 + nt*16 + l15] = f2b(acc[nt][r] + bias[nt]);
            }
    }
}

// ------------------------------------------------- pre_f GEMM: bf16 MFMA
// R5 epilogue layout:
// off = t*131072 + (b>>4)*16384 + (j>>4)*1024 + ((b&15)>>2)*256 + (b&3)*64
//       + (j&15)*4 + gate      where col = gate*256 + j
__global__ __launch_bounds__(256) void k_gemm_mfma(
    const __hip_bfloat16* __restrict__ A, const float* __restrict__ Bw,
    const float* __restrict__ bi1, const float* __restrict__ bi2,
    u16t* __restrict__ pre2)
{
    __shared__ u16t Asm[128][32];
    __shared__ u16t Bsm[128][32];
    const int tid = threadIdx.x;
    const int w = tid >> 6;
    const int l = tid & 63;
    const size_t m0 = (size_t)blockIdx.x * 128;
    const int n0 = blockIdx.y * 128;
    const int mw = (w >> 1) * 64;
    const int nw = (w & 1) * 64;

    f32x4 acc[4][4];
    #pragma unroll
    for (int s = 0; s < 4; ++s)
        #pragma unroll
        for (int t_ = 0; t_ < 4; ++t_)
            acc[s][t_] = (f32x4){0.f, 0.f, 0.f, 0.f};

    const u16t* Ab = (const u16t*)A;
    const int arow = w*32 + (l>>2);
    const int akoff = (l&3)*8;
    const int brow = w*32 + (l>>1);
    const int bko  = (l&1)*16;
    const int fr = l & 15, fq = (l >> 4) * 8;

    for (int kt = 0; kt < DD; kt += 32){
        gload16(Ab + (m0 + arow)*DD + kt + akoff,      &Asm[arow][akoff]);
        gload16(Ab + (m0 + arow + 16)*DD + kt + akoff, &Asm[arow+16][akoff]);
        const float* bp = Bw + (size_t)(n0 + brow)*DD + kt + bko;
        float4 f0 = *(const float4*)bp;
        float4 f1 = *(const float4*)(bp+4);
        float4 f2 = *(const float4*)(bp+8);
        float4 f3 = *(const float4*)(bp+12);
        uint4 o0, o1;
        o0.x = pack2(f0.x,f0.y); o0.y = pack2(f0.z,f0.w);
        o0.z = pack2(f1.x,f1.y); o0.w = pack2(f1.z,f1.w);
        o1.x = pack2(f2.x,f2.y); o1.y = pack2(f2.z,f2.w);
        o1.z = pack2(f3.x,f3.y); o1.w = pack2(f3.z,f3.w);
        *(uint4*)&Bsm[brow][bko]   = o0;
        *(uint4*)&Bsm[brow][bko+8] = o1;
        __syncthreads();

        bf16x8 af[4], bf[4];
        #pragma unroll
        for (int s = 0; s < 4; ++s) af[s] = *(const bf16x8*)&Asm[mw + s*16 + fr][fq];
        #pragma unroll
        for (int t_ = 0; t_ < 4; ++t_) bf[t_] = *(const bf16x8*)&Bsm[nw + t_*16 + fr][fq];
        #pragma unroll
        for (int s = 0; s < 4; ++s)
            #pragma unroll
            for (int t_ = 0; t_ < 4; ++t_)
                acc[s][t_] = __builtin_amdgcn_mfma_f32_16x16x32_bf16(af[s], bf[t_], acc[s][t_], 0, 0, 0);
        __syncthreads();
    }

    const int cr = (l >> 4) * 4;
    const int cc = l & 15;
    const int tIdx = blockIdx.x;   // rows are t-major: row = t*128 + b
    #pragma unroll
    for (int t_ = 0; t_ < 4; ++t_){
        int col = n0 + nw + t_*16 + cc;
        float bias = bi1[col] + bi2[col];
        int gate = col >> 8;
        int j    = col & 255;
        size_t cbase = (size_t)tIdx*131072 + (size_t)(j>>4)*1024 + (size_t)(j&15)*4 + gate;
        #pragma unroll
        for (int s = 0; s < 4; ++s)
            #pragma unroll
            for (int r = 0; r < 4; ++r){
                int b = mw + s*16 + cr + r;
                pre2[cbase + (size_t)(b>>4)*16384 + ((b&15)>>2)*256 + (b&3)*64]
                    = f2b(acc[s][t_][r] + bias);
            }
    }
}

// --------------------- backward LSTM: one step from zero state (unchanged)
__global__ __launch_bounds__(256) void k_lstm_b(
    const __hip_bfloat16* __restrict__ feats255,
    const float* __restrict__ Wih_b,
    const float* __restrict__ bih_b, const float* __restrict__ bhh_b,
    float* __restrict__ h_b)
{
    __shared__ float fs[DD];
    const int tid = threadIdx.x;
    const int b = blockIdx.x;
    const unsigned* fbu = (const unsigned*)(feats255 + (size_t)b * DD);
    for (int i = tid; i < DD/2; i += 256){
        unsigned u = fbu[i];
        fs[2*i] = lo2f(u); fs[2*i+1] = hi2f(u);
    }
    __syncthreads();

    const int w = tid >> 6, lane = tid & 63;
    const int j = blockIdx.y * 4 + w;
    const float* Wi = Wih_b + (size_t)j * DD;
    const float* Wg = Wih_b + (size_t)(512 + j) * DD;
    const float* Wo = Wih_b + (size_t)(768 + j) * DD;
    float si = 0.f, sg = 0.f, so = 0.f;
    #pragma unroll 2
    for (int i = 0; i < 34; ++i){
        int k = lane + i*64;
        float f = fs[k];
        si += f * Wi[k]; sg += f * Wg[k]; so += f * Wo[k];
    }
    #pragma unroll
    for (int off = 32; off > 0; off >>= 1){
        si += __shfl_down(si, off);
        sg += __shfl_down(sg, off);
        so += __shfl_down(so, off);
    }
    if (lane == 0){
        float zi = si + bih_b[j]       + bhh_b[j];
        float zg = sg + bih_b[512 + j] + bhh_b[512 + j];
        float zo = so + bih_b[768 + j] + bhh_b[768 + j];
        float c = sigm(zi) * tanhf(zg);
        h_b[(size_t)b*LHID + j] = sigm(zo) * tanhf(c);
    }
}

// ------------- forward LSTM R9: CU-local, h bf16 single, 1 barrier/step
// 8 WGs x 16 samples, 1024 threads (16 waves). Wave w owns j in
// [w*16, w*16+16) x 4 gates (nt=gate), full K=256. kc0-5 B-frags in VGPR,
// kc6-7 in LDS. hA double-buffered (write nxt, read cur -> one barrier).
__global__ __launch_bounds__(1024, 4) void k_lstm_f8(
    const u16t* __restrict__ pre2,            // R5 permuted layout
    const __hip_bfloat16* __restrict__ WTfrag,
    float* __restrict__ hout)                 // (128,256)
{
    __shared__ u16t Wl[65536];       // 128 KB: kc6-7 frags, [w][fi][lane][8]
    __shared__ u16t hA[2][16][264];  // 16.5 KB, double-buffered

    const int tid = threadIdx.x;
    const int w = tid >> 6, l = tid & 63;
    const int q = l >> 4, l15 = l & 15, q8 = q * 8;
    const int j = w*16 + l15;
    const int wg = blockIdx.x;
    const u16t* wtf = (const u16t*)WTfrag;

    // stage kc6-7 fragments into LDS (8 frags/wave x 16 waves = 128 KB)
    {
        const uint4* srcq = (const uint4*)wtf;
        uint4* dstq = (uint4*)Wl;
        for (int i = tid; i < 8192; i += 1024){
            int iw = i >> 9, fi = (i >> 6) & 7, il = i & 63;
            dstq[i] = srcq[(iw*32 + 24 + fi)*64 + il];
        }
    }
    for (int i = tid; i < 2*16*264; i += 1024)
        ((u16t*)hA)[i] = 0;

    // resident kc0-5 fragments: 24 frags = 96 VGPR
    bf16x8 Bv[6][4];
    #pragma unroll
    for (int kc = 0; kc < 6; ++kc)
        #pragma unroll
        for (int nt = 0; nt < 4; ++nt)
            Bv[kc][nt] = *(const bf16x8*)(wtf + (((size_t)(w*32 + kc*4 + nt))*64 + l)*8);

    float cst[4] = {0.f, 0.f, 0.f, 0.f};
    // pre2 lane base: wg*16384 + w*1024 + q*256 + r*64 + l15*4 (+ gate)
    const size_t pbase = (size_t)wg*16384 + (size_t)w*1024 + (size_t)q*256 + (size_t)l15*4;
    __syncthreads();

    #pragma unroll 1
    for (int t = 0; t < TT; ++t){
        const int tb = t & 1, nxt = tb ^ 1;

        // pre for this step: issue first, consumed after MFMA
        union { uint2 v; u16t s4[4]; } pr[4];
        {
            const u16t* pp = pre2 + (size_t)t*131072 + pbase;
            #pragma unroll
            for (int r = 0; r < 4; ++r) pr[r].v = *(const uint2*)(pp + r*64);
        }

        f32x4 acc[4];
        #pragma unroll
        for (int nt = 0; nt < 4; ++nt) acc[nt] = (f32x4){0.f,0.f,0.f,0.f};

        #pragma unroll
        for (int kc = 0; kc < 6; ++kc){
            bf16x8 ah = *(const bf16x8*)&hA[tb][l15][kc*32 + q8];
            #pragma unroll
            for (int nt = 0; nt < 4; ++nt)
                acc[nt] = __builtin_amdgcn_mfma_f32_16x16x32_bf16(ah, Bv[kc][nt], acc[nt], 0,0,0);
        }
        #pragma unroll
        for (int kc = 6; kc < 8; ++kc){
            bf16x8 ah = *(const bf16x8*)&hA[tb][l15][kc*32 + q8];
            #pragma unroll
            for (int nt = 0; nt < 4; ++nt){
                bf16x8 bL = *(const bf16x8*)&Wl[((w*8 + (kc-6)*4 + nt)*64 + l)*8];
                acc[nt] = __builtin_amdgcn_mfma_f32_16x16x32_bf16(ah, bL, acc[nt], 0,0,0);
            }
        }

        // gates
        #pragma unroll
        for (int r = 0; r < 4; ++r){
            float zi = acc[0][r] + b2f(pr[r].s4[0]);
            float zf = acc[1][r] + b2f(pr[r].s4[1]);
            float zg = acc[2][r] + b2f(pr[r].s4[2]);
            float zo = acc[3][r] + b2f(pr[r].s4[3]);
            float cn = fsig(zf)*cst[r] + fsig(zi)*ftanh(zg);
            cst[r] = cn;
            float hh = fsig(zo)*ftanh(cn);
            const int s = q*4 + r;
            if (t < TT - 1)
                hA[nxt][s][j] = f2b(hh);
            else
                hout[((size_t)wg*16 + s)*LHID + j] = hh;
        }
        __syncthreads();   // writes to hA[nxt] visible; hA[tb] reads all done
    }
}

// ----------------------------------------------------- head (unchanged)
__global__ __launch_bounds__(256) void k_head(
    const float* __restrict__ h_f, const float* __restrict__ h_b,
    const float* __restrict__ Wc, const float* __restrict__ bc,
    float* __restrict__ out)
{
    __shared__ float pool[512];
    const int b = blockIdx.x, tid = threadIdx.x;
    float p0 = fmaxf(h_f[(size_t)b*LHID + tid], 0.f);
    float p1 = fmaxf(h_b[(size_t)b*LHID + tid], 0.f);
    pool[tid] = p0; pool[256 + tid] = p1;
    out[(size_t)b*512 + tid]       = p0;
    out[(size_t)b*512 + 256 + tid] = p1;
    __syncthreads();
    for (int n = tid; n < NCLS; n += 256){
        float a = bc[n];
        const float* ww = Wc + (size_t)n * 512;
        #pragma unroll 4
        for (int k = 0; k < 512; k += 4){
            float4 wv = *(const float4*)(ww + k);
            a += pool[k]*wv.x + pool[k+1]*wv.y + pool[k+2]*wv.z + pool[k+3]*wv.w;
        }
        out[(size_t)BB*512 + (size_t)b*NCLS + n] = a;
    }
}

// ---------------------------------------------------------------------------
extern "C" void kernel_launch(void* const* d_in, const int* in_sizes, int n_in,
                              void* d_out, int out_size, void* d_ws, size_t ws_size,
                              hipStream_t stream) {
    const float* pose1 = (const float*)d_in[0];
    const float* pose2 = (const float*)d_in[1];
    const float* W1    = (const float*)d_in[2];
    const float* b1    = (const float*)d_in[3];
    const float* W2    = (const float*)d_in[4];
    const float* b2    = (const float*)d_in[5];
    const float* Wih_f = (const float*)d_in[6];
    const float* Whh_f = (const float*)d_in[7];
    const float* bih_f = (const float*)d_in[8];
    const float* bhh_f = (const float*)d_in[9];
    const float* Wih_b = (const float*)d_in[10];
    const float* bih_b = (const float*)d_in[12];
    const float* bhh_b = (const float*)d_in[13];
    const float* Wc    = (const float*)d_in[14];
    const float* bc    = (const float*)d_in[15];
    (void)in_sizes; (void)n_in; (void)out_size; (void)ws_size;
    float* out = (float*)d_out;
    char* ws = (char*)d_ws;

    // workspace (same 211,812,352-byte footprint)
    __hip_bfloat16* WTfrag = (__hip_bfloat16*)(ws + 0);           // 524,288
    __hip_bfloat16* W2Tb   = (__hip_bfloat16*)(ws + 524288);      //  32,768
    float*          h_b    = (float*)(ws + 557056);               // 131,072
    float*          h_f    = (float*)(ws + 688128);               // 131,072
    __hip_bfloat16* feats  = (__hip_bfloat16*)(ws + 2097152);     // 142,606,336
    u16t*           pre2   = (u16t*)(ws + 144703488);             //  67,108,864

    k_w2t     <<<64, 256, 0, stream>>>(W2, W2Tb);
    k_wfrag   <<<128, 256, 0, stream>>>(Whh_f, WTfrag);
    k_gcnfused<<<2048, 512, 0, stream>>>(pose1, pose2, W1, b1, b2, W2Tb, feats);
    k_gemm_mfma<<<dim3(256, 8), 256, 0, stream>>>(feats, Wih_f, bih_f, bhh_f, pre2);
    k_lstm_b  <<<dim3(128, 64), 256, 0, stream>>>(feats + (size_t)255*BB*DD, Wih_b, bih_b, bhh_b, h_b);
    k_lstm_f8 <<<8, 1024, 0, stream>>>(pre2, WTfrag, h_f);
    k_head    <<<128, 256, 0, stream>>>(h_f, h_b, Wc, bc, out);
}